// Round 9
// baseline (108.569 us; speedup 1.0000x reference)
//
#include <hip/hip_runtime.h>

// FFF tree traversal, round 9: HALF-WAVE ROWS. 2 rows per wave, 32 lanes per
// row, each lane owns 32 elements (8 f32x4). Butterfly reduce is 5 stages
// (masks 1..16, within-half) serving BOTH rows simultaneously -> 2.4x fewer
// shuffle-latency cycles per row; wave count halves (16384). Rolled level
// loop (round-8 proven: no spill). bf16 packed weights (proven numerics).
//
// Packing (per node, 128 u16x8 slots, slot s=q*32+j):
//   o[k]   = src[256q + 4j + k]        pairs xv[2q]
//   o[4+k] = src[256q + 128 + 4j + k]  pairs xv[2q+1]
// where xv[c] = row elements 128c + 4j .. +3  (f32x4 index c*32 + j).
// Sign safety: |score| < EPS -> fp32 recompute (half-uniform rare branch).

typedef float          f32x4 __attribute__((ext_vector_type(4)));
typedef unsigned short u16x8 __attribute__((ext_vector_type(8)));

#define FFF_BATCH  32768
#define FFF_NIN    1024
#define FFF_NOUT   1024
#define FFF_LEVELS 11
#define FFF_NODES  2047
#define FFF_EPS    0.01f
#define SLOTS      (FFF_NODES * 128)   // u16x8 slots per packed matrix

__device__ __forceinline__ f32x4 ld_nt4f(const f32x4* p) { return __builtin_nontemporal_load(p); }
__device__ __forceinline__ float upbf(unsigned short u) { return __uint_as_float((unsigned)u << 16); }
__device__ __forceinline__ unsigned short tobf(float f) {
    unsigned b = __float_as_uint(f);
    b = (b + 0x7FFFu + ((b >> 16) & 1u)) >> 16;   // round-to-nearest-even
    return (unsigned short)b;
}

// ---- prep: fp32 -> bf16 with the half-wave fragment permutation ----
__global__ void fff_pack_bf16(const float* __restrict__ w1, const float* __restrict__ w2,
                              u16x8* __restrict__ o1, u16x8* __restrict__ o2)
{
    int t = blockIdx.x * blockDim.x + threadIdx.x;
    const bool second = t >= SLOTS;
    if (second) t -= SLOTS;
    const float* src = second ? w2 : w1;
    u16x8*       dst = second ? o2 : o1;

    const int node = t >> 7;
    const int s    = t & 127;
    const int q    = s >> 5;
    const int j    = s & 31;

    const f32x4* sp = reinterpret_cast<const f32x4*>(src + (size_t)node * FFF_NIN);
    const f32x4 lo = sp[64 * q + j];        // elems 256q + 4j ..+3
    const f32x4 hi = sp[64 * q + 32 + j];   // elems 256q + 128 + 4j ..+3

    u16x8 o;
#pragma unroll
    for (int k = 0; k < 4; ++k) { o[k] = tobf(lo[k]); o[4 + k] = tobf(hi[k]); }
    dst[t] = o;
}

// ---- main fused kernel: 2 rows/wave (half-wave each), rolled level loop ----
__global__ __launch_bounds__(256, 4) void fff_main_bf16(
    const float* __restrict__ x,
    const u16x8* __restrict__ w1p,
    const float* __restrict__ w1f,   // fp32 w1 for the EPS fallback
    const u16x8* __restrict__ w2p,
    float*       __restrict__ y)
{
    const int wave = threadIdx.x >> 6;
    const int lane = threadIdx.x & 63;
    const int jl   = lane & 31;                       // lane within half
    const int row  = (blockIdx.x * 4 + wave) * 2 + (lane >> 5);

    // x: lane owns elements 128c + 4*jl ..+3 for c=0..7 (two 512B segs/instr)
    const f32x4* x4 = reinterpret_cast<const f32x4*>(x + (size_t)row * FFF_NIN);
    f32x4 xv[8];
#pragma unroll
    for (int c = 0; c < 8; ++c) xv[c] = ld_nt4f(&x4[c * 32 + jl]);

    f32x4 acc[8];
#pragma unroll
    for (int c = 0; c < 8; ++c) acc[c] = (f32x4)(0.f);

    int node = 0;

#pragma unroll 1
    for (int l = 0; l < FFF_LEVELS; ++l) {
        const u16x8* w1r = w1p + (size_t)node * 128;
        u16x8 a[4];
#pragma unroll
        for (int q = 0; q < 4; ++q) a[q] = w1r[q * 32 + jl];
        const u16x8* w2r = w2p + (size_t)node * 128;
        u16x8 b[4];
#pragma unroll
        for (int q = 0; q < 4; ++q) b[q] = w2r[q * 32 + jl];

        // dot: slot halves pair with xv[2q], xv[2q+1] by construction
        float p = 0.f;
#pragma unroll
        for (int q = 0; q < 4; ++q) {
#pragma unroll
            for (int k = 0; k < 4; ++k) {
                p = fmaf(xv[2 * q][k],     upbf(a[q][k]),     p);
                p = fmaf(xv[2 * q + 1][k], upbf(a[q][4 + k]), p);
            }
        }

        // 5-stage butterfly within each 32-lane half (both rows at once)
#pragma unroll
        for (int m = 1; m < 32; m <<= 1) p += __shfl_xor(p, m, 64);

        // rare half-uniform fp32 recompute for near-zero scores
        if (__builtin_expect(fabsf(p) < FFF_EPS, 0)) {
            const f32x4* w14 = reinterpret_cast<const f32x4*>(w1f + (size_t)node * FFF_NIN);
            float s = 0.f;
#pragma unroll
            for (int c = 0; c < 8; ++c) {
                const f32x4 w = w14[c * 32 + jl];
                s = fmaf(xv[c][0], w[0], s);
                s = fmaf(xv[c][1], w[1], s);
                s = fmaf(xv[c][2], w[2], s);
                s = fmaf(xv[c][3], w[3], s);
            }
#pragma unroll
            for (int m = 1; m < 32; m <<= 1) s += __shfl_xor(s, m, 64);
            p = s;
        }

        // accumulate y, advance node (per-lane; halves carry their own row)
#pragma unroll
        for (int q = 0; q < 4; ++q) {
#pragma unroll
            for (int k = 0; k < 4; ++k) {
                acc[2 * q][k]     = fmaf(p, upbf(b[q][k]),     acc[2 * q][k]);
                acc[2 * q + 1][k] = fmaf(p, upbf(b[q][4 + k]), acc[2 * q + 1][k]);
            }
        }
        node = node * 2 + 1 + ((p > 0.f) ? 1 : 0);
    }

    // y stores: same half-wave layout as x (two 512B segments per instr)
    f32x4* y4 = reinterpret_cast<f32x4*>(y + (size_t)row * FFF_NOUT);
#pragma unroll
    for (int c = 0; c < 8; ++c) y4[c * 32 + jl] = acc[c];
}

// ---- safety fallback: proven round-1 fp32 fused kernel ----
__global__ __launch_bounds__(256, 4) void fff_fused_f32(
    const float* __restrict__ x, const float* __restrict__ w1s,
    const float* __restrict__ w2s, float* __restrict__ y)
{
    const int row  = blockIdx.x * 4 + (threadIdx.x >> 6);
    const int lane = threadIdx.x & 63;
    const f32x4* x4 = reinterpret_cast<const f32x4*>(x + (size_t)row * FFF_NIN);
    f32x4 xv[4];
#pragma unroll
    for (int c = 0; c < 4; ++c) xv[c] = x4[c * 64 + lane];
    f32x4 acc[4];
#pragma unroll
    for (int c = 0; c < 4; ++c) acc[c] = (f32x4)(0.f);
    int node = 0;
#pragma unroll 1
    for (int l = 0; l < FFF_LEVELS; ++l) {
        const f32x4* w14 = reinterpret_cast<const f32x4*>(w1s + (size_t)node * FFF_NIN);
        const f32x4* w24 = reinterpret_cast<const f32x4*>(w2s + (size_t)node * FFF_NOUT);
        f32x4 wv[4], uv[4];
#pragma unroll
        for (int c = 0; c < 4; ++c) { wv[c] = w14[c * 64 + lane]; uv[c] = w24[c * 64 + lane]; }
        float p = 0.f;
#pragma unroll
        for (int c = 0; c < 4; ++c) {
            p = fmaf(xv[c][0], wv[c][0], p); p = fmaf(xv[c][1], wv[c][1], p);
            p = fmaf(xv[c][2], wv[c][2], p); p = fmaf(xv[c][3], wv[c][3], p);
        }
#pragma unroll
        for (int m = 1; m < 64; m <<= 1) p += __shfl_xor(p, m, 64);
#pragma unroll
        for (int c = 0; c < 4; ++c) {
            acc[c][0] = fmaf(p, uv[c][0], acc[c][0]); acc[c][1] = fmaf(p, uv[c][1], acc[c][1]);
            acc[c][2] = fmaf(p, uv[c][2], acc[c][2]); acc[c][3] = fmaf(p, uv[c][3], acc[c][3]);
        }
        node = node * 2 + 1 + ((p > 0.f) ? 1 : 0);
    }
    f32x4* y4 = reinterpret_cast<f32x4*>(y + (size_t)row * FFF_NOUT);
#pragma unroll
    for (int c = 0; c < 4; ++c) y4[c * 64 + lane] = acc[c];
}

extern "C" void kernel_launch(void* const* d_in, const int* in_sizes, int n_in,
                              void* d_out, int out_size, void* d_ws, size_t ws_size,
                              hipStream_t stream) {
    const float* x   = (const float*)d_in[0];
    const float* w1s = (const float*)d_in[1];
    const float* w2s = (const float*)d_in[2];
    float* y = (float*)d_out;

    const size_t wb_bytes = (size_t)SLOTS * sizeof(u16x8);   // 4,192,256
    const size_t need = 2 * wb_bytes;                        // 8,384,512

    if (ws_size >= need) {
        u16x8* w1p = (u16x8*)d_ws;
        u16x8* w2p = (u16x8*)((char*)d_ws + wb_bytes);
        fff_pack_bf16<<<2 * SLOTS / 256, 256, 0, stream>>>(w1s, w2s, w1p, w2p);
        // 4 waves/block x 2 rows/wave = 8 rows/block -> 4096 blocks
        fff_main_bf16<<<FFF_BATCH / 8, 256, 0, stream>>>(x, w1p, w1s, w2p, y);
    } else {
        fff_fused_f32<<<FFF_BATCH / 4, 256, 0, stream>>>(x, w1s, w2s, y);
    }
}

// Round 10
// 85.501 us; speedup vs baseline: 1.2698x; 1.2698x over previous
//
#include <hip/hip_runtime.h>

// FFF tree traversal, round 10: per-node-scaled biased-u8 weights.
// Rounds 8/9 both pinned at ~100 us moving 1.44 GB bf16 weights -> weight
// service BW (~14.4 TB/s scattered L2/L3) is the binding resource. u8 halves
// it to 0.72 GB. Uniform-distributed weights => linear int8 quant err
// sigma(score) ~ 2.3e-3 vs score sigma 0.58; EPS=0.02 (8.7 sigma) fp32
// fallback kills sign-flip risk. Biased-u8 + precomputed row-sum(x) keeps
// the dot at 2 VALU/elem (v_cvt_f32_ubyte + fma); w2 bias folds into one
// scalar corr subtracted at the end. Structure frozen at proven round 8:
// 1 row/wave, rolled level loop (no spill), nt x loads, plain y stores.

typedef float        f32x4 __attribute__((ext_vector_type(4)));
typedef unsigned int u32x4 __attribute__((ext_vector_type(4)));

#define FFF_BATCH  32768
#define FFF_NIN    1024
#define FFF_NOUT   1024
#define FFF_LEVELS 11
#define FFF_NODES  2047
#define FFF_EPS    0.02f

__device__ __forceinline__ f32x4 ld_nt4f(const f32x4* p) { return __builtin_nontemporal_load(p); }
__device__ __forceinline__ float ub(unsigned d, int k) {
    return (float)((d >> (8 * k)) & 0xffu);   // -> v_cvt_f32_ubyte[k]
}

// ---- prep: per-node u8 quantization of w1,w2 (one block per node) ----
// Output layout: byte b = 4*t + k of node's 1024B row <- src elem
// 256*(t&3) + 4*(t>>2) + k, i.e. in main, lane's dwords 4*lane..+3 (16B)
// pair elementwise with xv[c][k] = x[256c + 4*lane + k].
__global__ void fff_quant_u8(const float* __restrict__ w1, const float* __restrict__ w2,
                             unsigned char* __restrict__ q1, unsigned char* __restrict__ q2,
                             float* __restrict__ s1, float* __restrict__ s2)
{
    const int node = blockIdx.x;
    const int t    = threadIdx.x;          // 256
    const int wave = t >> 6;
    const int lane = t & 63;

    const f32x4* r1 = reinterpret_cast<const f32x4*>(w1 + (size_t)node * FFF_NIN);
    const f32x4* r2 = reinterpret_cast<const f32x4*>(w2 + (size_t)node * FFF_NOUT);
    const int si = 64 * (t & 3) + (t >> 2);
    const f32x4 v1 = r1[si];
    const f32x4 v2 = r2[si];

    float m1 = 0.f, m2 = 0.f;
#pragma unroll
    for (int k = 0; k < 4; ++k) {
        m1 = fmaxf(m1, fabsf(v1[k]));
        m2 = fmaxf(m2, fabsf(v2[k]));
    }
#pragma unroll
    for (int m = 1; m < 64; m <<= 1) {
        m1 = fmaxf(m1, __shfl_xor(m1, m, 64));
        m2 = fmaxf(m2, __shfl_xor(m2, m, 64));
    }
    __shared__ float sm1[4], sm2[4];
    if (lane == 0) { sm1[wave] = m1; sm2[wave] = m2; }
    __syncthreads();
    m1 = fmaxf(fmaxf(sm1[0], sm1[1]), fmaxf(sm1[2], sm1[3]));
    m2 = fmaxf(fmaxf(sm2[0], sm2[1]), fmaxf(sm2[2], sm2[3]));

    const float st1 = (m1 > 0.f) ? m1 / 127.f : 1.f;
    const float st2 = (m2 > 0.f) ? m2 / 127.f : 1.f;
    if (t == 0) { s1[node] = st1; s2[node] = st2; }

    unsigned d1 = 0, d2 = 0;
#pragma unroll
    for (int k = 0; k < 4; ++k) {
        const int u1 = (int)rintf(v1[k] / st1) + 128;   // in [1,255]
        const int u2 = (int)rintf(v2[k] / st2) + 128;
        d1 |= ((unsigned)u1 & 0xffu) << (8 * k);
        d2 |= ((unsigned)u2 & 0xffu) << (8 * k);
    }
    reinterpret_cast<unsigned*>(q1)[(size_t)node * 256 + t] = d1;
    reinterpret_cast<unsigned*>(q2)[(size_t)node * 256 + t] = d2;
}

// ---- main fused kernel: 1 row/wave, rolled level loop, u8 weights ----
__global__ __launch_bounds__(256, 4) void fff_main_u8(
    const float*         __restrict__ x,
    const unsigned char* __restrict__ q1,
    const float*         __restrict__ s1,
    const float*         __restrict__ w1f,   // fp32 w1 for the EPS fallback
    const unsigned char* __restrict__ q2,
    const float*         __restrict__ s2,
    float*               __restrict__ y)
{
    const int row  = blockIdx.x * 4 + (threadIdx.x >> 6);
    const int lane = threadIdx.x & 63;

    // coalesced x: xv[c] = elements 256c + 4*lane ..+3
    const f32x4* x4 = reinterpret_cast<const f32x4*>(x + (size_t)row * FFF_NIN);
    f32x4 xv[4];
#pragma unroll
    for (int c = 0; c < 4; ++c) xv[c] = ld_nt4f(&x4[c * 64 + lane]);

    // full-row sum of x (for the u8 bias correction), butterflied once
    float sumx = 0.f;
#pragma unroll
    for (int c = 0; c < 4; ++c) {
        sumx += xv[c][0]; sumx += xv[c][1]; sumx += xv[c][2]; sumx += xv[c][3];
    }
#pragma unroll
    for (int m = 1; m < 64; m <<= 1) sumx += __shfl_xor(sumx, m, 64);

    f32x4 acc[4];
#pragma unroll
    for (int c = 0; c < 4; ++c) acc[c] = (f32x4)(0.f);
    float corr = 0.f;

    int node = 0;

#pragma unroll 1
    for (int l = 0; l < FFF_LEVELS; ++l) {
        const int un = __builtin_amdgcn_readfirstlane(node);   // wave-uniform

        const u32x4 d1 = *reinterpret_cast<const u32x4*>(q1 + (size_t)un * 1024 + lane * 16);
        const u32x4 d2 = *reinterpret_cast<const u32x4*>(q2 + (size_t)un * 1024 + lane * 16);
        const float sc1 = s1[un];
        const float sc2 = s2[un];

        // u-space dot: pu = sum x_i * u_i  (u = w/step + 128)
        float pu = 0.f;
#pragma unroll
        for (int c = 0; c < 4; ++c) {
#pragma unroll
            for (int k = 0; k < 4; ++k)
                pu = fmaf(xv[c][k], ub(d1[c], k), pu);
        }
#pragma unroll
        for (int m = 1; m < 64; m <<= 1) pu += __shfl_xor(pu, m, 64);

        float p = (pu - 128.f * sumx) * sc1;

        // rare wave-uniform fp32 recompute for near-zero scores
        if (__builtin_expect(fabsf(p) < FFF_EPS, 0)) {
            const f32x4* w14 = reinterpret_cast<const f32x4*>(w1f + (size_t)un * FFF_NIN);
            float s = 0.f;
#pragma unroll
            for (int c = 0; c < 4; ++c) {
                const f32x4 w = w14[c * 64 + lane];
                s = fmaf(xv[c][0], w[0], s);
                s = fmaf(xv[c][1], w[1], s);
                s = fmaf(xv[c][2], w[2], s);
                s = fmaf(xv[c][3], w[3], s);
            }
#pragma unroll
            for (int m = 1; m < 64; m <<= 1) s += __shfl_xor(s, m, 64);
            p = s;
        }

        // y accumulate in u-space with folded scale; bias -> scalar corr
        const float s2l = p * sc2;
        corr = fmaf(s2l, 128.f, corr);
#pragma unroll
        for (int c = 0; c < 4; ++c) {
#pragma unroll
            for (int k = 0; k < 4; ++k)
                acc[c][k] = fmaf(s2l, ub(d2[c], k), acc[c][k]);
        }

        node = node * 2 + 1 + ((p > 0.f) ? 1 : 0);
    }

    // coalesced y stores, subtracting the uniform bias correction
    f32x4* y4 = reinterpret_cast<f32x4*>(y + (size_t)row * FFF_NOUT);
#pragma unroll
    for (int c = 0; c < 4; ++c) {
        f32x4 o;
        o[0] = acc[c][0] - corr; o[1] = acc[c][1] - corr;
        o[2] = acc[c][2] - corr; o[3] = acc[c][3] - corr;
        y4[c * 64 + lane] = o;
    }
}

// ---- safety fallback: proven round-1 fp32 fused kernel ----
__global__ __launch_bounds__(256, 4) void fff_fused_f32(
    const float* __restrict__ x, const float* __restrict__ w1s,
    const float* __restrict__ w2s, float* __restrict__ y)
{
    const int row  = blockIdx.x * 4 + (threadIdx.x >> 6);
    const int lane = threadIdx.x & 63;
    const f32x4* x4 = reinterpret_cast<const f32x4*>(x + (size_t)row * FFF_NIN);
    f32x4 xv[4];
#pragma unroll
    for (int c = 0; c < 4; ++c) xv[c] = x4[c * 64 + lane];
    f32x4 acc[4];
#pragma unroll
    for (int c = 0; c < 4; ++c) acc[c] = (f32x4)(0.f);
    int node = 0;
#pragma unroll 1
    for (int l = 0; l < FFF_LEVELS; ++l) {
        const f32x4* w14 = reinterpret_cast<const f32x4*>(w1s + (size_t)node * FFF_NIN);
        const f32x4* w24 = reinterpret_cast<const f32x4*>(w2s + (size_t)node * FFF_NOUT);
        f32x4 wv[4], uv[4];
#pragma unroll
        for (int c = 0; c < 4; ++c) { wv[c] = w14[c * 64 + lane]; uv[c] = w24[c * 64 + lane]; }
        float p = 0.f;
#pragma unroll
        for (int c = 0; c < 4; ++c) {
            p = fmaf(xv[c][0], wv[c][0], p); p = fmaf(xv[c][1], wv[c][1], p);
            p = fmaf(xv[c][2], wv[c][2], p); p = fmaf(xv[c][3], wv[c][3], p);
        }
#pragma unroll
        for (int m = 1; m < 64; m <<= 1) p += __shfl_xor(p, m, 64);
#pragma unroll
        for (int c = 0; c < 4; ++c) {
            acc[c][0] = fmaf(p, uv[c][0], acc[c][0]); acc[c][1] = fmaf(p, uv[c][1], acc[c][1]);
            acc[c][2] = fmaf(p, uv[c][2], acc[c][2]); acc[c][3] = fmaf(p, uv[c][3], acc[c][3]);
        }
        node = node * 2 + 1 + ((p > 0.f) ? 1 : 0);
    }
    f32x4* y4 = reinterpret_cast<f32x4*>(y + (size_t)row * FFF_NOUT);
#pragma unroll
    for (int c = 0; c < 4; ++c) y4[c * 64 + lane] = acc[c];
}

extern "C" void kernel_launch(void* const* d_in, const int* in_sizes, int n_in,
                              void* d_out, int out_size, void* d_ws, size_t ws_size,
                              hipStream_t stream) {
    const float* x   = (const float*)d_in[0];
    const float* w1s = (const float*)d_in[1];
    const float* w2s = (const float*)d_in[2];
    float* y = (float*)d_out;

    // ws layout (16B-aligned blocks): s1 | s2 | q1 | q2
    const size_t sc_bytes = 8192;                              // 2047 floats, padded
    const size_t q_bytes  = (size_t)FFF_NODES * 1024;          // 2,096,128
    const size_t need = 2 * sc_bytes + 2 * q_bytes;            // ~4.21 MB

    if (ws_size >= need) {
        float* s1 = (float*)d_ws;
        float* s2 = (float*)((char*)d_ws + sc_bytes);
        unsigned char* q1 = (unsigned char*)d_ws + 2 * sc_bytes;
        unsigned char* q2 = q1 + q_bytes;
        fff_quant_u8<<<FFF_NODES, 256, 0, stream>>>(w1s, w2s, q1, q2, s1, s2);
        fff_main_u8<<<FFF_BATCH / 4, 256, 0, stream>>>(x, q1, s1, w1s, q2, s2, y);
    } else {
        fff_fused_f32<<<FFF_BATCH / 4, 256, 0, stream>>>(x, w1s, w2s, y);
    }
}